// Round 2
// baseline (33.932 us; speedup 1.0000x reference)
//
#include <hip/hip_runtime.h>

// TransientGenerator, gather formulation.
// One block per (batch, 4096-sample super-chunk) = 4 sub-chunks of 1024.
// Per-batch transient metadata staged once in LDS as packed int2
// {(t_sample<<8)|id, gain_bits}; timings sorted -> binary search + early break.

constexpr int SR    = 16000;  // SAMPLE_RATE
constexpr int TL    = 1600;   // TRANSIENT_SAMPLES
constexpr int MAXT  = 256;    // MAX_TRANSIENTS
constexpr int SUB   = 1024;   // samples per sub-chunk (256 threads * 4)
constexpr int NSUB  = 4;
constexpr int SUPER = SUB * NSUB;

__global__ __launch_bounds__(256)
void transient_gather(const float* __restrict__ timings,   // [B,T]
                      const int*   __restrict__ ids,       // [B,T]
                      const float* __restrict__ gains,     // [B,T]
                      const float* __restrict__ templates, // [n_tr,TL]
                      float*       __restrict__ out,       // [B,A]
                      int T, int n_tr, int A)
{
    __shared__ int2 s_m[MAXT];   // .x = (clamped ts << 8) | clamped id ; .y = gain bits (0 if invalid)

    const int b     = blockIdx.y;
    const int super = blockIdx.x * SUPER;

    const float* bt = timings + (size_t)b * T;
    const float* bg = gains   + (size_t)b * T;
    const int*   bi = ids     + (size_t)b * T;

    for (int j = threadIdx.x; j < T; j += blockDim.x) {
        const float tm = bt[j];
        const int   ts = (int)floorf(tm * (float)SR);   // matches jnp.floor(t*SR) in fp32
        const float g  = bg[j];
        const int   id = bi[j];
        // reference: valid = (g>0) & (id<n_tr) & (ts<A); template index is clip(id,0,n_tr-1)
        const bool ok  = (g > 0.0f) & (id < n_tr) & (ts < A);
        const int  idc = min(max(id, 0), n_tr - 1);
        const int  tsc = min(ts, A);        // clamp keeps order; g==0 when ts>=A so value unused
        s_m[j] = make_int2((tsc << 8) | idc, ok ? __float_as_int(g) : 0);
    }
    __syncthreads();

    const int p0 = super + (int)threadIdx.x * 4;   // thread's first sample in sub-chunk 0
    float4 acc[NSUB];
#pragma unroll
    for (int k = 0; k < NSUB; ++k) acc[k] = make_float4(0.f, 0.f, 0.f, 0.f);

    // First j that can overlap: ts >= super - TL + 1  (packed compare, id bits don't matter)
    int lo = 0, hi = T;
    const int keyp = (super - TL + 1) << 8;
    while (lo < hi) { const int m = (lo + hi) >> 1; if (s_m[m].x < keyp) lo = m + 1; else hi = m; }

    const int endp = (super + SUPER) << 8;         // ts >= super_end -> nothing later overlaps
    for (int j = lo; j < T; ++j) {
        const int2 mj = s_m[j];
        if (mj.x >= endp) break;
        const int   ts = mj.x >> 8;
        const float g  = __int_as_float(mj.y);
        const float* __restrict__ row = templates + (size_t)(mj.x & 255) * TL;
#pragma unroll
        for (int k = 0; k < NSUB; ++k) {
            const int sub0 = super + k * SUB;
            if (ts >= sub0 + SUB || ts + TL <= sub0) continue;   // uniform skip (ts is block-uniform)
            const int off = p0 + k * SUB - ts;                   // this thread's offset into template
            if (off >= 0 && off + 3 < TL) {
                acc[k].x += g * row[off];
                acc[k].y += g * row[off + 1];
                acc[k].z += g * row[off + 2];
                acc[k].w += g * row[off + 3];
            } else if (off + 3 >= 0 && off < TL) {
                if (off     >= 0 && off     < TL) acc[k].x += g * row[off];
                if (off + 1 >= 0 && off + 1 < TL) acc[k].y += g * row[off + 1];
                if (off + 2 >= 0 && off + 2 < TL) acc[k].z += g * row[off + 2];
                if (off + 3 >= 0 && off + 3 < TL) acc[k].w += g * row[off + 3];
            }
        }
    }

#pragma unroll
    for (int k = 0; k < NSUB; ++k) {
        const int p = p0 + k * SUB;
        float* op = out + (size_t)b * A + p;
        if (p + 3 < A) {
            *reinterpret_cast<float4*>(op) = acc[k];   // out base 16B-aligned, p%4==0
        } else {
            if (p     < A) op[0] = acc[k].x;
            if (p + 1 < A) op[1] = acc[k].y;
            if (p + 2 < A) op[2] = acc[k].z;
            if (p + 3 < A) op[3] = acc[k].w;
        }
    }
}

extern "C" void kernel_launch(void* const* d_in, const int* in_sizes, int n_in,
                              void* d_out, int out_size, void* d_ws, size_t ws_size,
                              hipStream_t stream) {
    const float* timings   = (const float*)d_in[0];
    const int*   ids       = (const int*)  d_in[1];
    const float* gains     = (const float*)d_in[2];
    const float* templates = (const float*)d_in[3];
    float*       out       = (float*)d_out;

    const int T    = MAXT;                 // reference MAX_TRANSIENTS
    const int B    = in_sizes[0] / T;
    const int n_tr = in_sizes[3] / TL;     // templates are [n_tr, TL]
    const int A    = out_size / B;         // audio_length

    dim3 grid((A + SUPER - 1) / SUPER, B), block(256);
    transient_gather<<<grid, block, 0, stream>>>(timings, ids, gains, templates, out,
                                                 T, n_tr, A);
}

// Round 3
// 30.541 us; speedup vs baseline: 1.1110x; 1.1110x over previous
//
#include <hip/hip_runtime.h>

// TransientGenerator, gather formulation, two-phase:
//   prep   (B blocks): pack per-transient {(ts<<8)|id, gain} into ws; per
//          1024-chunk overlap range [lo,hi) via LDS binary search (sorted ts).
//   gather (B*nchunk blocks): no LDS/barrier/search/break — uniform scalar
//          meta loads + pipelined template loads + one float4 store.

constexpr int SR    = 16000;  // SAMPLE_RATE
constexpr int TL    = 1600;   // TRANSIENT_SAMPLES
constexpr int MAXT  = 256;    // MAX_TRANSIENTS
constexpr int CHUNK = 1024;   // samples per gather block (256 threads * 4)

__global__ __launch_bounds__(256)
void prep(const float* __restrict__ timings, const int* __restrict__ ids,
          const float* __restrict__ gains,
          int2* __restrict__ meta,      // [B,T]
          int2* __restrict__ ranges,    // [B,nchunk]
          int T, int n_tr, int A, int nchunk)
{
    __shared__ int s_ts[MAXT];
    const int b = blockIdx.x;

    for (int j = threadIdx.x; j < T; j += blockDim.x) {
        const float tm = timings[(size_t)b * T + j];
        const int   ts = (int)floorf(tm * (float)SR);   // matches jnp.floor(t*SR) fp32
        const float g  = gains[(size_t)b * T + j];
        const int   id = ids[(size_t)b * T + j];
        const bool ok  = (g > 0.0f) & (id < n_tr) & (ts < A);
        const int idc  = min(max(id, 0), n_tr - 1);
        const int tsc  = min(max(ts, 0), A);            // clamp preserves sorted order
        s_ts[j] = tsc;
        meta[(size_t)b * T + j] = make_int2((tsc << 8) | idc, ok ? __float_as_int(g) : 0);
    }
    __syncthreads();

    for (int c = threadIdx.x; c < nchunk; c += blockDim.x) {
        const int chunk = c * CHUNK;
        const int key_lo = max(0, chunk - TL + 1);      // first ts that can overlap
        const int key_hi = chunk + CHUNK;               // first ts past the chunk
        int lo = 0, hi = T;
        while (lo < hi) { const int m = (lo + hi) >> 1; if (s_ts[m] < key_lo) lo = m + 1; else hi = m; }
        int lo2 = lo, hi2 = T;
        while (lo2 < hi2) { const int m = (lo2 + hi2) >> 1; if (s_ts[m] < key_hi) lo2 = m + 1; else hi2 = m; }
        ranges[(size_t)b * nchunk + c] = make_int2(lo, lo2);
    }
}

__global__ __launch_bounds__(256)
void gather(const int2* __restrict__ meta, const int2* __restrict__ ranges,
            const float* __restrict__ templates, float* __restrict__ out,
            int T, int A, int nchunk)
{
    const int b     = blockIdx.y;
    const int c     = blockIdx.x;
    const int chunk = c * CHUNK;
    const int2 r    = ranges[(size_t)b * nchunk + c];   // uniform -> scalar load
    const int p0    = chunk + (int)threadIdx.x * 4;

    float4 acc = make_float4(0.f, 0.f, 0.f, 0.f);
    const int2* __restrict__ mb = meta + (size_t)b * T;

    for (int j = r.x; j < r.y; ++j) {                   // trip count known at entry, no break
        const int2  m  = mb[j];                         // uniform -> scalar load (K$)
        const int   ts = m.x >> 8;
        const float g  = __int_as_float(m.y);
        const float* __restrict__ row = templates + (size_t)(m.x & 255) * TL;
        const int off = p0 - ts;
        if (off >= 0 && off + 3 < TL) {
            acc.x += g * row[off];
            acc.y += g * row[off + 1];
            acc.z += g * row[off + 2];
            acc.w += g * row[off + 3];
        } else if (off + 3 >= 0 && off < TL) {
            if (off     >= 0 && off     < TL) acc.x += g * row[off];
            if (off + 1 >= 0 && off + 1 < TL) acc.y += g * row[off + 1];
            if (off + 2 >= 0 && off + 2 < TL) acc.z += g * row[off + 2];
            if (off + 3 >= 0 && off + 3 < TL) acc.w += g * row[off + 3];
        }
    }

    float* op = out + (size_t)b * A + p0;
    if (p0 + 3 < A) {
        *reinterpret_cast<float4*>(op) = acc;           // out base 16B-aligned, p0%4==0
    } else {
        if (p0     < A) op[0] = acc.x;
        if (p0 + 1 < A) op[1] = acc.y;
        if (p0 + 2 < A) op[2] = acc.z;
        if (p0 + 3 < A) op[3] = acc.w;
    }
}

// ---- fallback (R1 single-kernel path) if ws is too small ----
__global__ __launch_bounds__(256)
void gather_fb(const float* __restrict__ timings, const int* __restrict__ ids,
               const float* __restrict__ gains, const float* __restrict__ templates,
               float* __restrict__ out, int T, int n_tr, int A)
{
    __shared__ int2 s_m[MAXT];
    const int b = blockIdx.y;
    const int chunk = blockIdx.x * CHUNK;
    for (int j = threadIdx.x; j < T; j += blockDim.x) {
        const float tm = timings[(size_t)b * T + j];
        const int ts = (int)floorf(tm * (float)SR);
        const float g = gains[(size_t)b * T + j];
        const int id = ids[(size_t)b * T + j];
        const bool ok = (g > 0.0f) & (id < n_tr) & (ts < A);
        s_m[j] = make_int2((min(max(ts, 0), A) << 8) | min(max(id, 0), n_tr - 1),
                           ok ? __float_as_int(g) : 0);
    }
    __syncthreads();
    const int p0 = chunk + (int)threadIdx.x * 4;
    float4 acc = make_float4(0.f, 0.f, 0.f, 0.f);
    int lo = 0, hi = T;
    const int keyp = max(0, chunk - TL + 1) << 8;
    while (lo < hi) { const int m = (lo + hi) >> 1; if (s_m[m].x < keyp) lo = m + 1; else hi = m; }
    const int endp = (chunk + CHUNK) << 8;
    for (int j = lo; j < T; ++j) {
        const int2 m = s_m[j];
        if (m.x >= endp) break;
        const int ts = m.x >> 8;
        const float g = __int_as_float(m.y);
        const float* __restrict__ row = templates + (size_t)(m.x & 255) * TL;
        const int off = p0 - ts;
        if (off >= 0 && off + 3 < TL) {
            acc.x += g * row[off]; acc.y += g * row[off + 1];
            acc.z += g * row[off + 2]; acc.w += g * row[off + 3];
        } else if (off + 3 >= 0 && off < TL) {
            if (off     >= 0 && off     < TL) acc.x += g * row[off];
            if (off + 1 >= 0 && off + 1 < TL) acc.y += g * row[off + 1];
            if (off + 2 >= 0 && off + 2 < TL) acc.z += g * row[off + 2];
            if (off + 3 >= 0 && off + 3 < TL) acc.w += g * row[off + 3];
        }
    }
    float* op = out + (size_t)b * A + p0;
    if (p0 + 3 < A) { *reinterpret_cast<float4*>(op) = acc; }
    else {
        if (p0 < A) op[0] = acc.x;
        if (p0 + 1 < A) op[1] = acc.y;
        if (p0 + 2 < A) op[2] = acc.z;
        if (p0 + 3 < A) op[3] = acc.w;
    }
}

extern "C" void kernel_launch(void* const* d_in, const int* in_sizes, int n_in,
                              void* d_out, int out_size, void* d_ws, size_t ws_size,
                              hipStream_t stream) {
    const float* timings   = (const float*)d_in[0];
    const int*   ids       = (const int*)  d_in[1];
    const float* gains     = (const float*)d_in[2];
    const float* templates = (const float*)d_in[3];
    float*       out       = (float*)d_out;

    const int T      = MAXT;               // reference MAX_TRANSIENTS
    const int B      = in_sizes[0] / T;
    const int n_tr   = in_sizes[3] / TL;
    const int A      = out_size / B;
    const int nchunk = (A + CHUNK - 1) / CHUNK;

    const size_t need = (size_t)B * T * sizeof(int2) + (size_t)B * nchunk * sizeof(int2);
    if (ws_size >= need) {
        int2* meta   = (int2*)d_ws;
        int2* rangesp = meta + (size_t)B * T;
        prep<<<dim3(B), dim3(256), 0, stream>>>(timings, ids, gains, meta, rangesp,
                                                T, n_tr, A, nchunk);
        gather<<<dim3(nchunk, B), dim3(256), 0, stream>>>(meta, rangesp, templates, out,
                                                          T, A, nchunk);
    } else {
        gather_fb<<<dim3(nchunk, B), dim3(256), 0, stream>>>(timings, ids, gains,
                                                             templates, out, T, n_tr, A);
    }
}